// Round 11
// baseline (1143.128 us; speedup 1.0000x reference)
//
#include <hip/hip_runtime.h>
#include <hip/hip_bf16.h>
#include <hip/hip_cooperative_groups.h>

namespace cg = cooperative_groups;

#define EPS_BN 1e-5f

typedef __bf16 bf16_t;
typedef __bf16 bf16x8 __attribute__((ext_vector_type(8)));
typedef __bf16 bf16x4 __attribute__((ext_vector_type(4)));
typedef float fx4 __attribute__((ext_vector_type(4)));
typedef float floatx16 __attribute__((ext_vector_type(16)));

struct Params {
    const float *img, *q;
    const float *cw1, *cb1, *bg1, *bb1;
    const float *cw2, *cb2, *bg2, *bb2;
    const float *cw3, *cb3, *bg3, *bb3;
    const float *cw4, *cb4, *bg4, *bb4;
    const float *gw1, *gb1, *gw2, *gb2, *gw3, *gb3, *gw4, *gb4;
    const float *fw1, *fb1, *fw2, *fb2, *fw3, *fb3;
    float* out;
    float *x1, *x2, *x3, *x4, *U, *V, *wq, *part;
    float *p1, *p2, *p3, *p4, *scsh1, *scsh2, *scsh3, *biaspack;
    bf16_t* wpack;
};

// shared scratch: 8976 floats = 35904 B (largest user: conv2/3 tile 24*11*34)
#define SFLOATS 8976

// ---------------- prep work (wq + wpack + biaspack), unit = blk 0..63 ------
__device__ __forceinline__ void prep_fn(const Params& p, int blk, int t)
{
    {
        float acc = p.gb1[t];
        #pragma unroll
        for (int d = 0; d < 11; d++)
            acc = fmaf(p.q[blk * 11 + d], p.gw1[(52 + d) * 256 + t], acc);
        p.wq[blk * 256 + t] = acc;
    }
    if (blk == 0) {
        for (int idx = t; idx < 512; idx += 256) {
            int layer = idx >> 8;
            int rem = idx & 255;
            int cg2 = rem >> 5, l2 = (rem >> 4) & 1, reg = rem & 15;
            int c = cg2 * 32 + (reg & 3) + 8 * (reg >> 2) + 4 * l2;
            p.biaspack[idx] = (layer ? p.gb3 : p.gb2)[c];
        }
    }
    for (int f = blk * 384 + t; f < blk * 384 + 384; f += 256) {
        int lane = f & 63;
        int kt = (f >> 6) & 15;
        int cg2 = (f >> 10) & 7;
        int layer = f >> 13;
        const float* gw = (layer == 0) ? p.gw2 : ((layer == 1) ? p.gw3 : p.gw4);
        int col = (cg2 << 5) + (lane & 31);
        int kb = kt * 16 + (lane >> 5) * 8;
        bf16x8 o;
        #pragma unroll
        for (int e = 0; e < 8; e++)
            o[e] = (bf16_t)gw[(kb + e) * 256 + col];
        *(bf16x8*)&p.wpack[(size_t)f * 8] = o;
    }
}

// ---------------- unified conv tile ----------------
template<int CIN, int HOUT, int TOX, int TOY, int CO_PER, bool FOLD>
__device__ __forceinline__ void conv_tile(
    float* tin, const float* scf, const float* shf, float (&red)[4][48],
    const float* in, const float* w, const float* bias,
    float* out, float* part_out, int u, int t)
{
    const int HIN = 2 * HOUT, ROWS = 2 * TOY + 3, RW = 2 * TOX + 2;
    const int TX = HOUT / TOX, TY = HOUT / TOY;
    const int WPC = (TOX * TOY) / 64;
    int b = u / (TX * TY);
    int rem = u % (TX * TY);
    int ty = rem / TX, tx = rem % TX;
    int oy0 = ty * TOY, ox0 = tx * TOX;
    const int total = CIN * ROWS * RW;
    int iyb = 2 * oy0 - 1, ixb = 2 * ox0 - 1;
    #pragma unroll 2
    for (int idx = t; idx < total; idx += 256) {
        int rx = idx % RW;
        int r2 = idx / RW;
        int ry = r2 % ROWS;
        int ci = r2 / ROWS;
        int iy = iyb + ry, ix = ixb + rx;
        float v = 0.f;
        if ((unsigned)iy < (unsigned)HIN && (unsigned)ix < (unsigned)HIN) {
            float raw = in[(b * CIN + ci) * HIN * HIN + iy * HIN + ix];
            v = FOLD ? fmaf(raw, scf[ci], shf[ci]) : raw;
        }
        tin[(ci * ROWS + ry) * RW + rx] = v;
    }
    __syncthreads();
    int ox = t % TOX;
    int oyl = (t / TOX) % TOY;
    int cog = t / (TOX * TOY);               // wave-uniform
    const float* wp = w + cog * CO_PER * CIN * 9;
    float acc[CO_PER];
    #pragma unroll
    for (int r = 0; r < CO_PER; r++) acc[r] = bias[cog * CO_PER + r];
    for (int ci = 0; ci < CIN; ci++)
        #pragma unroll
        for (int ky = 0; ky < 3; ky++)
            #pragma unroll
            for (int kx = 0; kx < 3; kx++) {
                float v = tin[(ci * ROWS + 2 * oyl + ky) * RW + 2 * ox + kx];
                #pragma unroll
                for (int r = 0; r < CO_PER; r++)
                    acc[r] = fmaf(v, wp[(r * CIN + ci) * 9 + ky * 3 + kx], acc[r]);
            }
    int oy = oy0 + oyl;
    float s1[CO_PER], s2[CO_PER];
    #pragma unroll
    for (int r = 0; r < CO_PER; r++) {
        float v = fmaxf(acc[r], 0.f);
        out[((b * 24 + cog * CO_PER + r) * HOUT + oy) * HOUT + ox0 + ox] = v;
        s1[r] = v;
        s2[r] = v * v;
    }
    int lane = t & 63, w_id = t >> 6;
    #pragma unroll
    for (int r = 0; r < CO_PER; r++) {
        float a = s1[r], c2 = s2[r];
        #pragma unroll
        for (int off = 32; off > 0; off >>= 1) {
            a += __shfl_xor(a, off);
            c2 += __shfl_xor(c2, off);
        }
        if (lane == 0) { red[w_id][r * 2] = a; red[w_id][r * 2 + 1] = c2; }
    }
    __syncthreads();
    if (t < 48) {
        int ch = t >> 1, st = t & 1;
        int cg2 = ch / CO_PER, r = ch % CO_PER;
        float v = 0.f;
        #pragma unroll
        for (int k = 0; k < WPC; k++) v += red[cg2 * WPC + k][r * 2 + st];
        part_out[u * 48 + t] = v;
    }
    __syncthreads();
}

// ---------------- BN finalize (unit = channel c) ----------------
__device__ __forceinline__ void fin_fn(
    const float* part, int Pn, float inv_n, const float* gamma,
    const float* beta, float* scsh, float (&red)[4][48], int c, int t)
{
    float s1 = 0.f, s2 = 0.f;
    for (int pr = t; pr < Pn; pr += 256) {
        s1 += part[pr * 48 + 2 * c];
        s2 += part[pr * 48 + 2 * c + 1];
    }
    #pragma unroll
    for (int off = 32; off > 0; off >>= 1) {
        s1 += __shfl_xor(s1, off);
        s2 += __shfl_xor(s2, off);
    }
    int lane = t & 63, w = t >> 6;
    if (lane == 0) { red[w][0] = s1; red[w][1] = s2; }
    __syncthreads();
    if (t == 0) {
        float a1 = red[0][0] + red[1][0] + red[2][0] + red[3][0];
        float a2 = red[0][1] + red[1][1] + red[2][1] + red[3][1];
        float m = a1 * inv_n;
        float var = a2 * inv_n - m * m;
        float sc = gamma[c] * rsqrtf(var + EPS_BN);
        scsh[c] = sc;
        scsh[24 + c] = fmaf(-m, sc, beta[c]);
    }
    __syncthreads();
}

// ---------------- U/V (inline BN4 finalize from p4, P=64) ----------------
__device__ __forceinline__ void uv_fn(
    float* o, float (&fred)[5][48], float* scf, float* shf,
    const Params& p, int u, int t)
{
    int b = u >> 2, n0 = (u & 3) * 16;
    if (t < 240) {
        int comp = t % 48, sl = t / 48;
        float a = 0.f;
        for (int pr = sl; pr < 64; pr += 5) a += p.p4[pr * 48 + comp];
        fred[sl][comp] = a;
    }
    __syncthreads();
    if (t < 24) {
        float s1 = 0.f, s2 = 0.f;
        #pragma unroll
        for (int s = 0; s < 5; s++) { s1 += fred[s][2 * t]; s2 += fred[s][2 * t + 1]; }
        float m = s1 * (1.f / 4096.f);
        float var = s2 * (1.f / 4096.f) - m * m;
        float sc = p.bg4[t] * rsqrtf(var + EPS_BN);
        scf[t] = sc;
        shf[t] = fmaf(-m, sc, p.bb4[t]);
    }
    __syncthreads();
    for (int idx = t; idx < 16 * 26; idx += 256) {
        int n = idx / 26, f = idx % 26;
        int ng = n0 + n;
        float val;
        if (f < 24)
            val = fmaf(p.x4[(b * 24 + f) * 64 + ng], scf[f], shf[f]);
        else if (f == 24) val = (float)(ng >> 3) * 0.125f;
        else              val = (float)(ng & 7) * 0.125f;
        o[n * 26 + f] = val;
    }
    __syncthreads();
    float g1u[26], g1v[26];
    #pragma unroll
    for (int f = 0; f < 26; f++) {
        g1u[f] = p.gw1[f * 256 + t];
        g1v[f] = p.gw1[(26 + f) * 256 + t];
    }
    for (int n = 0; n < 16; n++) {
        float uu = 0.f, vv = 0.f;
        #pragma unroll
        for (int f = 0; f < 26; f++) {
            float of = o[n * 26 + f];
            uu = fmaf(of, g1u[f], uu);
            vv = fmaf(of, g1v[f], vv);
        }
        int ng = n0 + n;
        p.U[(b * 64 + ng) * 256 + t] = uu;
        p.V[(b * 64 + ng) * 256 + t] = vv;
    }
    __syncthreads();
}

// ---------------- pair unit (R9 design; hA = bf16[64][264] flat) ----------
__device__ __forceinline__ void pair_fn(bf16_t* hA, const Params& p, int u, int t)
{
    int b = u >> 6, i = u & 63;
    __syncthreads();   // prior hA use complete
    {
        int cc = t & 31, jg = t >> 5;
        int c0 = cc * 8;
        const float* Ub = p.U + (b * 64 + i) * 256 + c0;
        const float* Qb = p.wq + b * 256 + c0;
        fx4 u0 = *(const fx4*)Ub + *(const fx4*)Qb;
        fx4 u1 = *(const fx4*)(Ub + 4) + *(const fx4*)(Qb + 4);
        const float* Vb = p.V + (b * 64) * 256 + c0;
        #pragma unroll
        for (int r = 0; r < 8; r++) {
            int j = jg * 8 + r;
            const float* Vr = Vb + j * 256;
            fx4 v0 = *(const fx4*)Vr + u0;
            fx4 v1 = *(const fx4*)(Vr + 4) + u1;
            bf16x8 o;
            #pragma unroll
            for (int e = 0; e < 4; e++) {
                o[e]     = (bf16_t)fmaxf(v0[e], 0.f);
                o[e + 4] = (bf16_t)fmaxf(v1[e], 0.f);
            }
            *(bf16x8*)&hA[j * 264 + c0] = o;
        }
    }
    __syncthreads();

    int lane = t & 63, wave = t >> 6;
    int l31 = lane & 31, l2 = lane >> 5;
    const floatx16 zero16 = {0.f, 0.f, 0.f, 0.f, 0.f, 0.f, 0.f, 0.f,
                             0.f, 0.f, 0.f, 0.f, 0.f, 0.f, 0.f, 0.f};

    int cm = wave;
    #pragma unroll 1
    for (int lay = 0; lay < 2; lay++) {
        floatx16 acc[2][2];
        #pragma unroll
        for (int mt = 0; mt < 2; mt++)
            #pragma unroll
            for (int nt = 0; nt < 2; nt++) acc[mt][nt] = zero16;
        const bf16_t* W0 = p.wpack + ((size_t)(lay * 8 + cm * 2) * 1024 + lane) * 8;
        const bf16_t* W1 = W0 + 8192;
        bf16x8 Aq[4][2];
        #pragma unroll
        for (int pr = 0; pr < 4; pr++) {
            Aq[pr][0] = *(const bf16x8*)(W0 + pr * 512);
            Aq[pr][1] = *(const bf16x8*)(W1 + pr * 512);
        }
        #pragma unroll
        for (int ks = 0; ks < 16; ks++) {
            int slot = ks & 3;
            bf16x8 a0 = Aq[slot][0];
            bf16x8 a1 = Aq[slot][1];
            if (ks < 12) {
                Aq[slot][0] = *(const bf16x8*)(W0 + (ks + 4) * 512);
                Aq[slot][1] = *(const bf16x8*)(W1 + (ks + 4) * 512);
            }
            bf16x8 b0 = *(const bf16x8*)&hA[l31 * 264 + ks * 16 + l2 * 8];
            bf16x8 b1 = *(const bf16x8*)&hA[(32 + l31) * 264 + ks * 16 + l2 * 8];
            acc[0][0] = __builtin_amdgcn_mfma_f32_32x32x16_bf16(a0, b0, acc[0][0], 0, 0, 0);
            acc[0][1] = __builtin_amdgcn_mfma_f32_32x32x16_bf16(a0, b1, acc[0][1], 0, 0, 0);
            acc[1][0] = __builtin_amdgcn_mfma_f32_32x32x16_bf16(a1, b0, acc[1][0], 0, 0, 0);
            acc[1][1] = __builtin_amdgcn_mfma_f32_32x32x16_bf16(a1, b1, acc[1][1], 0, 0, 0);
        }
        __syncthreads();
        #pragma unroll
        for (int mt = 0; mt < 2; mt++) {
            const fx4* bp = (const fx4*)(p.biaspack + lay * 256 + (cm * 2 + mt) * 32 + l2 * 16);
            fx4 bv[4];
            #pragma unroll
            for (int g = 0; g < 4; g++) bv[g] = bp[g];
            int cb = cm * 64 + mt * 32 + 4 * l2;
            #pragma unroll
            for (int nt = 0; nt < 2; nt++) {
                int j = nt * 32 + l31;
                #pragma unroll
                for (int g = 0; g < 4; g++) {
                    bf16x4 o;
                    #pragma unroll
                    for (int r = 0; r < 4; r++)
                        o[r] = (bf16_t)fmaxf(acc[mt][nt][g * 4 + r] + bv[g][r], 0.f);
                    *(bf16x4*)&hA[j * 264 + cb + 8 * g] = o;
                }
            }
        }
        __syncthreads();
    }

    int cn = wave;
    {
        float bcol[2] = {p.gb4[cn * 64 + l31], p.gb4[cn * 64 + 32 + l31]};
        floatx16 acc[2][2];
        #pragma unroll
        for (int mt = 0; mt < 2; mt++)
            #pragma unroll
            for (int nt = 0; nt < 2; nt++) acc[mt][nt] = zero16;
        const bf16_t* B0 = p.wpack + ((size_t)(16 + cn * 2) * 1024 + lane) * 8;
        const bf16_t* B1 = B0 + 8192;
        bf16x8 Bq[4][2];
        #pragma unroll
        for (int pr = 0; pr < 4; pr++) {
            Bq[pr][0] = *(const bf16x8*)(B0 + pr * 512);
            Bq[pr][1] = *(const bf16x8*)(B1 + pr * 512);
        }
        #pragma unroll
        for (int ks = 0; ks < 16; ks++) {
            int slot = ks & 3;
            bf16x8 w0 = Bq[slot][0];
            bf16x8 w1 = Bq[slot][1];
            if (ks < 12) {
                Bq[slot][0] = *(const bf16x8*)(B0 + (ks + 4) * 512);
                Bq[slot][1] = *(const bf16x8*)(B1 + (ks + 4) * 512);
            }
            bf16x8 a0 = *(const bf16x8*)&hA[l31 * 264 + ks * 16 + l2 * 8];
            bf16x8 a1 = *(const bf16x8*)&hA[(32 + l31) * 264 + ks * 16 + l2 * 8];
            acc[0][0] = __builtin_amdgcn_mfma_f32_32x32x16_bf16(a0, w0, acc[0][0], 0, 0, 0);
            acc[1][0] = __builtin_amdgcn_mfma_f32_32x32x16_bf16(a1, w0, acc[1][0], 0, 0, 0);
            acc[0][1] = __builtin_amdgcn_mfma_f32_32x32x16_bf16(a0, w1, acc[0][1], 0, 0, 0);
            acc[1][1] = __builtin_amdgcn_mfma_f32_32x32x16_bf16(a1, w1, acc[1][1], 0, 0, 0);
        }
        float colsum[2];
        #pragma unroll
        for (int nt = 0; nt < 2; nt++) {
            float s = 0.f;
            #pragma unroll
            for (int mt = 0; mt < 2; mt++)
                #pragma unroll
                for (int reg = 0; reg < 16; reg++)
                    s += fmaxf(acc[mt][nt][reg] + bcol[nt], 0.0f);
            colsum[nt] = s;
        }
        #pragma unroll
        for (int nt = 0; nt < 2; nt++)
            colsum[nt] += __shfl_xor(colsum[nt], 32);
        if (l2 == 0) {
            #pragma unroll
            for (int nt = 0; nt < 2; nt++)
                p.part[u * 256 + cn * 64 + nt * 32 + l31] = colsum[nt];
        }
    }
}

// ---------------- f_phi unit ----------------
__device__ __forceinline__ void fphi_fn(float* ff, const Params& p, int b, int t)
{
    float* g  = ff;
    float* h1 = ff + 256;
    float* h2 = ff + 512;
    __syncthreads();
    float s = 0.f;
    for (int k = 0; k < 64; k++) s += p.part[(b * 64 + k) * 256 + t];
    g[t] = s * (1.0f / 4096.0f);
    __syncthreads();
    float a1 = p.fb1[t];
    for (int k = 0; k < 256; k++) a1 = fmaf(g[k], p.fw1[k * 256 + t], a1);
    h1[t] = fmaxf(a1, 0.0f);
    __syncthreads();
    float a2 = p.fb2[t];
    for (int k = 0; k < 256; k++) a2 = fmaf(h1[k], p.fw2[k * 256 + t], a2);
    h2[t] = fmaxf(a2, 0.0f);
    __syncthreads();
    if (t < 10) {
        float a3 = p.fb3[t];
        for (int k = 0; k < 256; k++) a3 = fmaf(h2[k], p.fw3[k * 10 + t], a3);
        p.out[b * 10 + t] = a3;
    }
}

// ---------------- cooperative mega-kernel ----------------
__global__ __launch_bounds__(256, 4) void mega_kernel(Params p)
{
    __shared__ __align__(16) float S[SFLOATS];
    __shared__ float scf[24], shf[24];
    __shared__ float red[4][48];
    __shared__ float fred[5][48];
    cg::grid_group grid = cg::this_grid();
    const int blk = blockIdx.x, t = threadIdx.x, G = gridDim.x;

    for (int u = blk; u < 2048; u += G)
        conv_tile<3, 64, 64, 2, 12, false>(S, scf, shf, red,
            p.img, p.cw1, p.cb1, p.x1, p.p1, u, t);
    if (blk < 64) prep_fn(p, blk, t);
    grid.sync();
    if (blk < 24) fin_fn(p.p1, 2048, 1.f / 262144.f, p.bg1, p.bb1, p.scsh1, red, blk, t);
    grid.sync();

    if (t < 24) { scf[t] = p.scsh1[t]; shf[t] = p.scsh1[24 + t]; }
    __syncthreads();
    for (int u = blk; u < 1024; u += G)
        conv_tile<24, 32, 16, 4, 6, true>(S, scf, shf, red,
            p.x1, p.cw2, p.cb2, p.x2, p.p2, u, t);
    grid.sync();
    if (blk < 24) fin_fn(p.p2, 1024, 1.f / 65536.f, p.bg2, p.bb2, p.scsh2, red, blk, t);
    grid.sync();

    if (t < 24) { scf[t] = p.scsh2[t]; shf[t] = p.scsh2[24 + t]; }
    __syncthreads();
    for (int u = blk; u < 256; u += G)
        conv_tile<24, 16, 16, 4, 6, true>(S, scf, shf, red,
            p.x2, p.cw3, p.cb3, p.x3, p.p3, u, t);
    grid.sync();
    if (blk < 24) fin_fn(p.p3, 256, 1.f / 16384.f, p.bg3, p.bb3, p.scsh3, red, blk, t);
    grid.sync();

    if (t < 24) { scf[t] = p.scsh3[t]; shf[t] = p.scsh3[24 + t]; }
    __syncthreads();
    for (int u = blk; u < 64; u += G)
        conv_tile<24, 8, 8, 8, 6, true>(S, scf, shf, red,
            p.x3, p.cw4, p.cb4, p.x4, p.p4, u, t);
    grid.sync();

    for (int u = blk; u < 256; u += G) uv_fn(S, fred, scf, shf, p, u, t);
    grid.sync();

    for (int u = blk; u < 4096; u += G) pair_fn((bf16_t*)S, p, u, t);
    grid.sync();

    for (int u = blk; u < 64; u += G) fphi_fn(S, p, u, t);
}

// ---------------- fallback wrappers (same device fns, separate launches) ---
__global__ __launch_bounds__(256) void fb_c1prep(Params p)
{
    __shared__ __align__(16) float S[SFLOATS];
    __shared__ float scf[24], shf[24];
    __shared__ float red[4][48];
    int t = threadIdx.x;
    if (blockIdx.x >= 2048) { prep_fn(p, blockIdx.x - 2048, t); return; }
    conv_tile<3, 64, 64, 2, 12, false>(S, scf, shf, red,
        p.img, p.cw1, p.cb1, p.x1, p.p1, blockIdx.x, t);
}

__global__ __launch_bounds__(256) void fb_fin(
    const float* part, int Pn, float inv_n, const float* gamma,
    const float* beta, float* scsh)
{
    __shared__ float red[4][48];
    fin_fn(part, Pn, inv_n, gamma, beta, scsh, red, blockIdx.x, threadIdx.x);
}

template<int CIN, int HOUT, int TOX, int TOY, int CO_PER>
__global__ __launch_bounds__(256) void fb_conv(
    const float* in, const float* scsh, const float* w, const float* bias,
    float* out, float* part_out)
{
    __shared__ __align__(16) float S[SFLOATS];
    __shared__ float scf[24], shf[24];
    __shared__ float red[4][48];
    int t = threadIdx.x;
    if (t < 24) { scf[t] = scsh[t]; shf[t] = scsh[24 + t]; }
    __syncthreads();
    conv_tile<CIN, HOUT, TOX, TOY, CO_PER, true>(S, scf, shf, red,
        in, w, bias, out, part_out, blockIdx.x, t);
}

__global__ __launch_bounds__(256) void fb_uv(Params p)
{
    __shared__ __align__(16) float S[SFLOATS];
    __shared__ float scf[24], shf[24];
    __shared__ float fred[5][48];
    uv_fn(S, fred, scf, shf, p, blockIdx.x, threadIdx.x);
}

__global__ __launch_bounds__(256, 3) void fb_pair(Params p)
{
    __shared__ __align__(16) bf16_t hA[64 * 264];
    pair_fn(hA, p, blockIdx.x, threadIdx.x);
}

__global__ __launch_bounds__(256) void fb_fphi(Params p)
{
    __shared__ __align__(16) float ff[768];
    fphi_fn(ff, p, blockIdx.x, threadIdx.x);
}

extern "C" void kernel_launch(void* const* d_in, const int* in_sizes, int n_in,
                              void* d_out, int out_size, void* d_ws, size_t ws_size,
                              hipStream_t stream)
{
    (void)in_sizes; (void)n_in; (void)out_size; (void)ws_size;
    float* ws = (float*)d_ws;
    Params p;
    p.img = (const float*)d_in[0];
    p.q   = (const float*)d_in[1];
    p.cw1 = (const float*)d_in[2];  p.cb1 = (const float*)d_in[3];
    p.bg1 = (const float*)d_in[4];  p.bb1 = (const float*)d_in[5];
    p.cw2 = (const float*)d_in[6];  p.cb2 = (const float*)d_in[7];
    p.bg2 = (const float*)d_in[8];  p.bb2 = (const float*)d_in[9];
    p.cw3 = (const float*)d_in[10]; p.cb3 = (const float*)d_in[11];
    p.bg3 = (const float*)d_in[12]; p.bb3 = (const float*)d_in[13];
    p.cw4 = (const float*)d_in[14]; p.cb4 = (const float*)d_in[15];
    p.bg4 = (const float*)d_in[16]; p.bb4 = (const float*)d_in[17];
    p.gw1 = (const float*)d_in[18]; p.gb1 = (const float*)d_in[19];
    p.gw2 = (const float*)d_in[20]; p.gb2 = (const float*)d_in[21];
    p.gw3 = (const float*)d_in[22]; p.gb3 = (const float*)d_in[23];
    p.gw4 = (const float*)d_in[24]; p.gb4 = (const float*)d_in[25];
    p.fw1 = (const float*)d_in[26]; p.fb1 = (const float*)d_in[27];
    p.fw2 = (const float*)d_in[28]; p.fb2 = (const float*)d_in[29];
    p.fw3 = (const float*)d_in[30]; p.fb3 = (const float*)d_in[31];
    p.out = (float*)d_out;

    p.x1 = ws;                        // 6291456
    p.x2 = p.x1 + 6291456;            // 1572864
    p.x3 = p.x2 + 1572864;            // 393216
    p.x4 = p.x3 + 393216;             // 98304
    p.U  = p.x4 + 98304;              // 1048576
    p.V  = p.U + 1048576;             // 1048576
    p.wq = p.V + 1048576;             // 16384
    p.part = p.wq + 16384;            // 1048576
    p.p1 = p.part + 1048576;          // 2048*48
    p.p2 = p.p1 + 98304;              // 1024*48
    p.p3 = p.p2 + 49152;              // 256*48
    p.p4 = p.p3 + 12288;              // 64*48
    p.scsh1 = p.p4 + 3072;            // 48
    p.scsh2 = p.scsh1 + 48;           // 48
    p.scsh3 = p.scsh2 + 48;           // 48
    p.biaspack = p.scsh3 + 48;        // 512
    p.wpack = (bf16_t*)(p.biaspack + 512);  // 3*65536 bf16

    // ---- attempt cooperative mega-kernel with driver-clamped grid ----
    hipError_t e = hipErrorUnknown;
    int dev = 0;
    if (hipGetDevice(&dev) == hipSuccess) {
        int numCU = 0, maxB = 0;
        hipDeviceGetAttribute(&numCU, hipDeviceAttributeMultiprocessorCount, dev);
        hipError_t qe = hipOccupancyMaxActiveBlocksPerMultiprocessor(
            &maxB, mega_kernel, 256, 0);
        long G = (qe == hipSuccess && numCU > 0) ? (long)numCU * maxB : 0;
        if (G > 1024) G = 1024;
        if (G >= 64) {
            void* args[] = { &p };
            e = hipLaunchCooperativeKernel((const void*)mega_kernel,
                                           dim3((unsigned)G), dim3(256),
                                           args, 0, stream);
        }
    }
    if (e != hipSuccess) {
        // ---- fallback: multi-kernel chain (known-good R9 structure) ----
        fb_c1prep<<<2112, 256, 0, stream>>>(p);
        fb_fin<<<24, 256, 0, stream>>>(p.p1, 2048, 1.f / 262144.f, p.bg1, p.bb1, p.scsh1);
        fb_conv<24, 32, 16, 4, 6><<<1024, 256, 0, stream>>>(
            p.x1, p.scsh1, p.cw2, p.cb2, p.x2, p.p2);
        fb_fin<<<24, 256, 0, stream>>>(p.p2, 1024, 1.f / 65536.f, p.bg2, p.bb2, p.scsh2);
        fb_conv<24, 16, 16, 4, 6><<<256, 256, 0, stream>>>(
            p.x2, p.scsh2, p.cw3, p.cb3, p.x3, p.p3);
        fb_fin<<<24, 256, 0, stream>>>(p.p3, 256, 1.f / 16384.f, p.bg3, p.bb3, p.scsh3);
        fb_conv<24, 8, 8, 8, 6><<<64, 256, 0, stream>>>(
            p.x3, p.scsh3, p.cw4, p.cb4, p.x4, p.p4);
        fb_uv<<<256, 256, 0, stream>>>(p);
        fb_pair<<<4096, 256, 0, stream>>>(p);
        fb_fphi<<<64, 256, 0, stream>>>(p);
    }
}